// Round 3
// baseline (46.141 us; speedup 1.0000x reference)
//
#include <hip/hip_runtime.h>
#include <math.h>

// Problem constants (from setup_inputs): xcorr [32, 3, 64, 4096] fp32, nlag = 2048.
#define NB 32
#define NC 3
#define NX 64
#define NT 4096
#define NGRID 201

__device__ __forceinline__ bool better(float va, int ia, float vb, int ib) {
    // lexicographic: larger value wins; tie -> lower index wins (lax.top_k stability)
    return (va > vb) || (va == vb && ia < ib);
}

// One block per (b, x). Single scan pass interleaves the 3 channel rows
// (3 independent float4 loads per k-iteration, no barriers in the scan),
// keeping per-channel top-2 state + top-1 neighbor values in registers.
// One reduction tail per block: per-channel wave butterfly -> LDS -> wave0
// merges, parabolic 201-pt grid argmax per channel, channel select, write.
__global__ __launch_bounds__(256) void detect_peaks_kernel(
    const float* __restrict__ xcorr,
    const int*   __restrict__ nlag_p,
    float* __restrict__ out)
{
    __shared__ float sv0[NC][4], sv1[NC][4], snm[NC][4], snp[NC][4];
    __shared__ int   si0[NC][4], si1[NC][4];

    const int bid  = blockIdx.x;          // (b, x)
    const int b    = bid / NX;
    const int x    = bid % NX;
    const int tid  = threadIdx.x;
    const int lane = tid & 63;
    const int wid  = tid >> 6;

    const float* __restrict__ xr0 =
        xcorr + ((size_t)(b * NC) * NX + x) * NT;   // channel stride = NX*NT

    // per-channel running state (all indices compile-time after unroll)
    float v0[NC], v1[NC], n0m[NC], n0p[NC];
    int   i0[NC], i1[NC];
    #pragma unroll
    for (int c = 0; c < NC; ++c) {
        v0[c] = -1.0f; v1[c] = -1.0f;
        i0[c] = 0x7fffffff; i1[c] = 0x7fffffff;
        n0m[c] = 0.0f; n0p[c] = 0.0f;
    }

    // ---- single interleaved scan: 12 float4 loads/thread, zero barriers ----
    #pragma unroll
    for (int k = 0; k < 4; ++k) {
        const int t4 = (k * 256 + tid) * 4;       // first element of this float4
        #pragma unroll
        for (int c = 0; c < NC; ++c) {
            const float* __restrict__ xr = xr0 + (size_t)c * (NX * NT);
            const float4 v = *reinterpret_cast<const float4*>(xr + t4);
            const float a0 = fabsf(v.x), a1 = fabsf(v.y);
            const float a2 = fabsf(v.z), a3 = fabsf(v.w);

            // cross-float4 neighbors via wave shuffle; wave-edge lanes refetch
            float lm = __shfl_up(a3, 1);
            float rm = __shfl_down(a0, 1);
            if (lane == 0 && t4 > 0)        lm = fabsf(xr[t4 - 1]);
            if (lane == 63 && t4 + 4 < NT)  rm = fabsf(xr[t4 + 4]);
            const bool has_l = (t4 > 0);
            const bool has_r = (t4 + 4 < NT);
            const float cmp_l = has_l ? lm : -INFINITY;
            const float cmp_r = has_r ? rm : -INFINITY;
            const float par_l = has_l ? lm : a0;   // clipped neighbor value (jnp.clip)
            const float par_r = has_r ? rm : a3;

            // keep = (x == 3-tap max); candidate = x*keep (zeros stay, like ref)
            const float c0 = (a0 >= cmp_l && a0 >= a1) ? a0 : 0.0f;
            const float c1 = (a1 >= a0 && a1 >= a2) ? a1 : 0.0f;
            const float c2 = (a2 >= a1 && a2 >= a3) ? a2 : 0.0f;
            const float c3 = (a3 >= a2 && a3 >= cmp_r) ? a3 : 0.0f;

            // top-2 insert in ascending-index order; track top-1's neighbors
            if (c0 > v0[c])      { v1[c]=v0[c]; i1[c]=i0[c]; v0[c]=c0; i0[c]=t4;   n0m[c]=par_l; n0p[c]=a1; }
            else if (c0 > v1[c]) { v1[c]=c0; i1[c]=t4; }
            if (c1 > v0[c])      { v1[c]=v0[c]; i1[c]=i0[c]; v0[c]=c1; i0[c]=t4+1; n0m[c]=a0; n0p[c]=a2; }
            else if (c1 > v1[c]) { v1[c]=c1; i1[c]=t4+1; }
            if (c2 > v0[c])      { v1[c]=v0[c]; i1[c]=i0[c]; v0[c]=c2; i0[c]=t4+2; n0m[c]=a1; n0p[c]=a3; }
            else if (c2 > v1[c]) { v1[c]=c2; i1[c]=t4+2; }
            if (c3 > v0[c])      { v1[c]=v0[c]; i1[c]=i0[c]; v0[c]=c3; i0[c]=t4+3; n0m[c]=a2; n0p[c]=par_r; }
            else if (c3 > v1[c]) { v1[c]=c3; i1[c]=t4+3; }
        }
    }

    // ---- per-channel wave butterfly top-2 merge (carry top-1 neighbors) ----
    #pragma unroll
    for (int c = 0; c < NC; ++c) {
        #pragma unroll
        for (int off = 1; off < 64; off <<= 1) {
            const float ov0 = __shfl_xor(v0[c], off);
            const int   oi0 = __shfl_xor(i0[c], off);
            const float ov1 = __shfl_xor(v1[c], off);
            const int   oi1 = __shfl_xor(i1[c], off);
            const float onm = __shfl_xor(n0m[c], off);
            const float onp = __shfl_xor(n0p[c], off);
            if (better(ov0, oi0, v0[c], i0[c])) {
                float nv1; int ni1;
                if (better(v0[c], i0[c], ov1, oi1)) { nv1 = v0[c]; ni1 = i0[c]; }
                else                                { nv1 = ov1;   ni1 = oi1;   }
                v0[c] = ov0; i0[c] = oi0; n0m[c] = onm; n0p[c] = onp;
                v1[c] = nv1; i1[c] = ni1;
            } else {
                if (better(ov0, oi0, v1[c], i1[c])) { v1[c] = ov0; i1[c] = oi0; }
            }
        }
        if (lane == 0) {
            sv0[c][wid] = v0[c]; si0[c][wid] = i0[c];
            sv1[c][wid] = v1[c]; si1[c][wid] = i1[c];
            snm[c][wid] = n0m[c]; snp[c][wid] = n0p[c];
        }
    }
    __syncthreads();

    // ---- wave 0: merge 4 wave results per channel, grid argmax, select ----
    if (tid < 64) {
        float best_w = -INFINITY, best_s = 0.0f, best_f = 0.0f;

        #pragma unroll
        for (int c = 0; c < NC; ++c) {
            float m0 = sv0[c][0], m1 = sv1[c][0];
            int  mi0 = si0[c][0], mi1 = si1[c][0];
            float nm = snm[c][0], np = snp[c][0];
            #pragma unroll
            for (int w = 1; w < 4; ++w) {
                const float b0 = sv0[c][w], b1 = sv1[c][w];
                const int  bi0 = si0[c][w], bi1 = si1[c][w];
                if (better(b0, bi0, m0, mi0)) {
                    float nv1; int ni1;
                    if (better(m0, mi0, b1, bi1)) { nv1 = m0; ni1 = mi0; }
                    else                          { nv1 = b1; ni1 = bi1; }
                    m0 = b0; mi0 = bi0; nm = snm[c][w]; np = snp[c][w];
                    m1 = nv1; mi1 = ni1;
                } else {
                    if (better(b0, bi0, m1, mi1)) { m1 = b0; mi1 = bi0; }
                }
            }

            const float s0 = m0, s1 = m1;
            const float weight = (0.1f + 3.0f * (s0 - s1)) * (s0 * s0);

            // parabola through (clipped) neighbors, tracked during the scan
            const float A = 0.5f * (nm + np) - s0;
            const float B = 0.5f * (np - nm);
            const float C = s0;

            // grid argmax over xg = linspace(-1,1,201)
            float bv = -INFINITY; int bi = 0x7fffffff;
            #pragma unroll
            for (int k = 0; k < 4; ++k) {
                const int gi = lane + k * 64;
                if (gi < NGRID) {
                    const float xg = 0.01f * (float)(gi - 100);
                    const float yg = (A * xg + B) * xg + C;
                    if (yg > bv) { bv = yg; bi = gi; }   // strict > = first occurrence
                }
            }
            #pragma unroll
            for (int off = 1; off < 64; off <<= 1) {
                const float ov = __shfl_xor(bv, off);
                const int   oi = __shfl_xor(bi, off);
                if (ov > bv || (ov == bv && oi < bi)) { bv = ov; bi = oi; }
            }

            // channel argmax (ascending c + strict > == first occurrence)
            if (weight > best_w) {
                best_w = weight;
                best_s = bv;
                best_f = (float)mi0 + 0.01f * (float)(bi - 100);
            }
        }

        if (lane == 0) {
            const float nlagf = (float)(*nlag_p);
            const int n = NB * NX;
            const int o = b * NX + x;
            const float shift_idx = best_f - nlagf;
            out[0 * n + o] = best_s;              // max_cc (interpolated score)
            out[1 * n + o] = best_w;              // weight
            out[2 * n + o] = shift_idx / 100.0f;  // shift_t (SAMPLING_RATE = 100)
            out[3 * n + o] = shift_idx;           // shift_idx
        }
    }
}

extern "C" void kernel_launch(void* const* d_in, const int* in_sizes, int n_in,
                              void* d_out, int out_size, void* d_ws, size_t ws_size,
                              hipStream_t stream) {
    const float* xcorr  = (const float*)d_in[0];
    const int*   nlag_p = (const int*)d_in[1];
    float* out = (float*)d_out;

    detect_peaks_kernel<<<NB * NX, 256, 0, stream>>>(xcorr, nlag_p, out);
}

// Round 4
// 25.081 us; speedup vs baseline: 1.8397x; 1.8397x over previous
//
#include <hip/hip_runtime.h>
#include <math.h>

// Problem constants (from setup_inputs): xcorr [32, 3, 64, 4096] fp32, nlag = 2048.
#define NB 32
#define NC 3
#define NX 64
#define NT 4096
#define CH_STRIDE ((size_t)NX * NT)

struct Quad { float4 a, b, c, d; };

__device__ __forceinline__ Quad load_row(const float* __restrict__ xr, int wid, int lane) {
    const float* base = xr + (size_t)(wid << 10) + (size_t)(lane << 2);
    Quad q;
    q.a = *reinterpret_cast<const float4*>(base);
    q.b = *reinterpret_cast<const float4*>(base + 256);
    q.c = *reinterpret_cast<const float4*>(base + 512);
    q.d = *reinterpret_cast<const float4*>(base + 768);
    return q;
}

// Branch-free top-2 over 4 consecutive elements. v1 is value-only (its index is
// never needed by the weight formula). Strict > keeps the lowest index on ties,
// matching lax.top_k; equal-to-max duplicates land in v1 via fmax (s1 == s0).
__device__ __forceinline__ void proc4(float a0, float a1, float a2, float a3,
                                      float cl, float cr, int t4,
                                      float& v0, int& i0, float& v1)
{
    // keep = (x == 3-tap max); candidate = x*keep (zeros stay candidates, like ref)
    const float c0 = (a0 >= cl && a0 >= a1) ? a0 : 0.0f;
    const float c1 = (a1 >= a0 && a1 >= a2) ? a1 : 0.0f;
    const float c2 = (a2 >= a1 && a2 >= a3) ? a2 : 0.0f;
    const float c3 = (a3 >= a2 && a3 >= cr) ? a3 : 0.0f;
    bool g;
    g = c0 > v0; v1 = g ? v0 : fmaxf(v1, c0); v0 = fmaxf(v0, c0); i0 = g ? t4     : i0;
    g = c1 > v0; v1 = g ? v0 : fmaxf(v1, c1); v0 = fmaxf(v0, c1); i0 = g ? t4 + 1 : i0;
    g = c2 > v0; v1 = g ? v0 : fmaxf(v1, c2); v0 = fmaxf(v0, c2); i0 = g ? t4 + 2 : i0;
    g = c3 > v0; v1 = g ? v0 : fmaxf(v1, c3); v0 = fmaxf(v0, c3); i0 = g ? t4 + 3 : i0;
}

// Scan one 4096-lag row held in q (wave-contiguous mapping: this wave covers
// [wid*1024, wid*1024+1024), lane covers 4 consecutive elems per group).
// Returns wave-merged (v0 value, i0 index, v1 value) identical in all lanes.
__device__ __forceinline__ void scan_row(Quad q, const float* __restrict__ xr,
                                         int wid, int lane,
                                         float& v0, int& i0, float& v1)
{
    const int base = (wid << 10) + (lane << 2);
    v0 = -1.0f; v1 = -1.0f; i0 = 0;

    const float a00 = fabsf(q.a.x), a01 = fabsf(q.a.y), a02 = fabsf(q.a.z), a03 = fabsf(q.a.w);
    const float a10 = fabsf(q.b.x), a11 = fabsf(q.b.y), a12 = fabsf(q.b.z), a13 = fabsf(q.b.w);
    const float a20 = fabsf(q.c.x), a21 = fabsf(q.c.y), a22 = fabsf(q.c.z), a23 = fabsf(q.c.w);
    const float a30 = fabsf(q.d.x), a31 = fabsf(q.d.y), a32 = fabsf(q.d.z), a33 = fabsf(q.d.w);

    // cross-wave edge values: uniform clamped loads (broadcast, 1 line each)
    const float lmf = fabsf(xr[(wid > 0) ? (wid << 10) - 1 : 0]);
    const float rmf = fabsf(xr[(wid < 3) ? ((wid + 1) << 10) : NT - 1]);

    float lm, rm, t;

    // group 0
    lm = __shfl_up(a03, 1);
    lm = (lane == 0) ? ((wid > 0) ? lmf : -INFINITY) : lm;
    rm = __shfl_down(a00, 1);
    t  = __shfl(a10, 0);
    rm = (lane == 63) ? t : rm;
    proc4(a00, a01, a02, a03, lm, rm, base, v0, i0, v1);

    // group 1
    lm = __shfl_up(a13, 1);
    t  = __shfl(a03, 63);
    lm = (lane == 0) ? t : lm;
    rm = __shfl_down(a10, 1);
    t  = __shfl(a20, 0);
    rm = (lane == 63) ? t : rm;
    proc4(a10, a11, a12, a13, lm, rm, base + 256, v0, i0, v1);

    // group 2
    lm = __shfl_up(a23, 1);
    t  = __shfl(a13, 63);
    lm = (lane == 0) ? t : lm;
    rm = __shfl_down(a20, 1);
    t  = __shfl(a30, 0);
    rm = (lane == 63) ? t : rm;
    proc4(a20, a21, a22, a23, lm, rm, base + 512, v0, i0, v1);

    // group 3
    lm = __shfl_up(a33, 1);
    t  = __shfl(a23, 63);
    lm = (lane == 0) ? t : lm;
    rm = __shfl_down(a30, 1);
    rm = (lane == 63) ? ((wid < 3) ? rmf : -INFINITY) : rm;
    proc4(a30, a31, a32, a33, lm, rm, base + 768, v0, i0, v1);

    // wave butterfly top-2 merge (lexicographic on (value desc, index asc))
    #pragma unroll
    for (int off = 1; off < 64; off <<= 1) {
        const float ov0 = __shfl_xor(v0, off);
        const int   oi0 = __shfl_xor(i0, off);
        const float ov1 = __shfl_xor(v1, off);
        const bool big = (ov0 > v0) || (ov0 == v0 && oi0 < i0);
        const float loser = big ? v0 : ov0;
        v1 = fmaxf(fmaxf(v1, ov1), loser);
        v0 = big ? ov0 : v0;
        i0 = big ? oi0 : i0;
    }
}

// Merge the 4 per-wave results of one channel (LDS slots, uniform reads).
__device__ __forceinline__ void merge4(const float sv0c[4], const int si0c[4],
                                       const float sv1c[4],
                                       float& m0, int& mi, float& m1)
{
    m0 = sv0c[0]; mi = si0c[0]; m1 = sv1c[0];
    #pragma unroll
    for (int w = 1; w < 4; ++w) {
        const float b0 = sv0c[w]; const int bi = si0c[w]; const float b1 = sv1c[w];
        const bool big = (b0 > m0) || (b0 == m0 && bi < mi);
        const float loser = big ? m0 : b0;
        m1 = fmaxf(fmaxf(m1, b1), loser);
        m0 = big ? b0 : m0;
        mi = big ? bi : mi;
    }
}

__global__ __launch_bounds__(256) void detect_peaks_kernel(
    const float* __restrict__ xcorr,
    const int*   __restrict__ nlag_p,
    float* __restrict__ out)
{
    __shared__ float sv0[NC][4], sv1[NC][4];
    __shared__ int   si0[NC][4];

    const int bid  = blockIdx.x;           // (b, x)
    const int b    = bid >> 6;
    const int x    = bid & 63;
    const int tid  = threadIdx.x;
    const int lane = tid & 63;
    const int wid  = tid >> 6;

    const float* __restrict__ xr0 = xcorr + ((size_t)(b * NC) * NX + x) * NT;
    const float* __restrict__ xr1 = xr0 + CH_STRIDE;
    const float* __restrict__ xr2 = xr0 + 2 * CH_STRIDE;

    Quad q0 = load_row(xr0, wid, lane);
    Quad q1 = load_row(xr1, wid, lane);

    float v0, v1; int i0;

    scan_row(q0, xr0, wid, lane, v0, i0, v1);
    Quad q2 = load_row(xr2, wid, lane);     // issue ch2 loads before ch0 tail
    if (lane == 0) { sv0[0][wid] = v0; si0[0][wid] = i0; sv1[0][wid] = v1; }

    scan_row(q1, xr1, wid, lane, v0, i0, v1);
    if (lane == 0) { sv0[1][wid] = v0; si0[1][wid] = i0; sv1[1][wid] = v1; }

    scan_row(q2, xr2, wid, lane, v0, i0, v1);
    if (lane == 0) { sv0[2][wid] = v0; si0[2][wid] = i0; sv1[2][wid] = v1; }

    __syncthreads();   // the only barrier in the kernel

    // uniform epilogue (all threads redundantly; tid 0 writes)
    float m00, m01, m02, m10, m11, m12; int p0, p1, p2;
    merge4(sv0[0], si0[0], sv1[0], m00, p0, m10);
    merge4(sv0[1], si0[1], sv1[1], m01, p1, m11);
    merge4(sv0[2], si0[2], sv1[2], m02, p2, m12);

    const float w0 = (0.1f + 3.0f * (m00 - m10)) * (m00 * m00);
    const float w1 = (0.1f + 3.0f * (m01 - m11)) * (m01 * m01);
    const float w2 = (0.1f + 3.0f * (m02 - m12)) * (m02 * m02);

    // channel argmax, first occurrence (ascending c, strict >) — branch-free
    const bool t1 = w1 > w0;
    float bw = t1 ? w1 : w0;
    float bs = t1 ? m01 : m00;
    int   bp = t1 ? p1 : p0;
    const float* xrs = t1 ? xr1 : xr0;
    const bool t2 = w2 > bw;
    bw  = t2 ? w2 : bw;
    bs  = t2 ? m02 : bs;
    bp  = t2 ? p2 : bp;
    xrs = t2 ? xr2 : xrs;

    if (tid == 0) {
        // parabola through clipped neighbors of the selected peak
        const float ym1 = fabsf(xrs[bp > 0 ? bp - 1 : 0]);
        const float yp1 = fabsf(xrs[bp < NT - 1 ? bp + 1 : NT - 1]);
        const float A = 0.5f * (ym1 + yp1) - bs;   // <= 0 up to FP rounding
        const float B = 0.5f * (yp1 - ym1);
        const float C = bs;

        // closed-form grid argmax of yg=(A*xg+B)*xg+C over xg=linspace(-1,1,201):
        // evaluate the 4 grid points bracketing the vertex with the SAME FP
        // formula as the reference; first-max tie-break (ascending candidates).
        int gi; float bv;
        if (A == 0.0f) {
            gi = (B > 0.0f) ? 200 : 0;
            const float xg = 0.01f * (float)(gi - 100);
            bv = (A * xg + B) * xg + C;
        } else {
            float gv = (1.0f - 0.5f * B / A) * 100.0f;  // vertex in grid coords
            gv = fminf(fmaxf(gv, 0.0f), 200.0f);
            const int glo = (int)gv;
            bv = -INFINITY; gi = 0;
            #pragma unroll
            for (int d = -1; d <= 2; ++d) {
                int g = glo + d;
                g = g < 0 ? 0 : (g > 200 ? 200 : g);
                const float xg = 0.01f * (float)(g - 100);
                const float yg = (A * xg + B) * xg + C;
                if (yg > bv) { bv = yg; gi = g; }       // strict > = first occurrence
            }
        }

        const float fidx = (float)bp + 0.01f * (float)(gi - 100);
        const float nlagf = (float)(*nlag_p);
        const float shift_idx = fidx - nlagf;
        const int n = NB * NX;
        const int o = b * NX + x;
        out[0 * n + o] = bv;                  // max_cc (interpolated score)
        out[1 * n + o] = bw;                  // weight
        out[2 * n + o] = shift_idx / 100.0f;  // shift_t (SAMPLING_RATE = 100)
        out[3 * n + o] = shift_idx;           // shift_idx
    }
}

extern "C" void kernel_launch(void* const* d_in, const int* in_sizes, int n_in,
                              void* d_out, int out_size, void* d_ws, size_t ws_size,
                              hipStream_t stream) {
    const float* xcorr  = (const float*)d_in[0];
    const int*   nlag_p = (const int*)d_in[1];
    float* out = (float*)d_out;

    detect_peaks_kernel<<<NB * NX, 256, 0, stream>>>(xcorr, nlag_p, out);
}

// Round 6
// 25.080 us; speedup vs baseline: 1.8398x; 1.0001x over previous
//
#include <hip/hip_runtime.h>
#include <math.h>

// Problem constants (from setup_inputs): xcorr [32, 3, 64, 4096] fp32, nlag = 2048.
#define NB 32
#define NC 3
#define NX 64
#define NT 4096
#define CH_STRIDE ((size_t)NX * NT)

struct Quad { float4 a, b, c, d; };

__device__ __forceinline__ Quad load_row(const float* __restrict__ xr, int wid, int lane) {
    const float* base = xr + (size_t)(wid << 10) + (size_t)(lane << 2);
    Quad q;
    q.a = *reinterpret_cast<const float4*>(base);
    q.b = *reinterpret_cast<const float4*>(base + 256);
    q.c = *reinterpret_cast<const float4*>(base + 512);
    q.d = *reinterpret_cast<const float4*>(base + 768);
    return q;
}

// Branch-free top-2 over 4 consecutive elements. v1 is value-only (its index is
// never needed by the weight formula). Strict > keeps the lowest index on ties,
// matching lax.top_k; equal-to-max duplicates land in v1 via fmax (s1 == s0).
__device__ __forceinline__ void proc4(float a0, float a1, float a2, float a3,
                                      float cl, float cr, int t4,
                                      float& v0, int& i0, float& v1)
{
    // keep = (x == 3-tap max); candidate = x*keep (zeros stay candidates, like ref)
    const float c0 = (a0 >= cl && a0 >= a1) ? a0 : 0.0f;
    const float c1 = (a1 >= a0 && a1 >= a2) ? a1 : 0.0f;
    const float c2 = (a2 >= a1 && a2 >= a3) ? a2 : 0.0f;
    const float c3 = (a3 >= a2 && a3 >= cr) ? a3 : 0.0f;
    bool g;
    g = c0 > v0; v1 = g ? v0 : fmaxf(v1, c0); v0 = fmaxf(v0, c0); i0 = g ? t4     : i0;
    g = c1 > v0; v1 = g ? v0 : fmaxf(v1, c1); v0 = fmaxf(v0, c1); i0 = g ? t4 + 1 : i0;
    g = c2 > v0; v1 = g ? v0 : fmaxf(v1, c2); v0 = fmaxf(v0, c2); i0 = g ? t4 + 2 : i0;
    g = c3 > v0; v1 = g ? v0 : fmaxf(v1, c3); v0 = fmaxf(v0, c3); i0 = g ? t4 + 3 : i0;
}

// Scan one 4096-lag row held in q (wave-contiguous mapping: this wave covers
// [wid*1024, wid*1024+1024), lane covers 4 consecutive elems per group).
// Edge values lmf/rmf (|x| at wid*1024-1 and wid*1024+1024, preloaded) are
// used only for wid>0 / wid<3 respectively.
// Returns wave-merged (v0 value, i0 index, v1 value) identical in all lanes.
__device__ __forceinline__ void scan_row(Quad q, float lmf, float rmf,
                                         int wid, int lane,
                                         float& v0, int& i0, float& v1)
{
    const int base = (wid << 10) + (lane << 2);
    v0 = -1.0f; v1 = -1.0f; i0 = 0;

    const float a00 = fabsf(q.a.x), a01 = fabsf(q.a.y), a02 = fabsf(q.a.z), a03 = fabsf(q.a.w);
    const float a10 = fabsf(q.b.x), a11 = fabsf(q.b.y), a12 = fabsf(q.b.z), a13 = fabsf(q.b.w);
    const float a20 = fabsf(q.c.x), a21 = fabsf(q.c.y), a22 = fabsf(q.c.z), a23 = fabsf(q.c.w);
    const float a30 = fabsf(q.d.x), a31 = fabsf(q.d.y), a32 = fabsf(q.d.z), a33 = fabsf(q.d.w);

    float lm, rm, t;

    // group 0
    lm = __shfl_up(a03, 1);
    lm = (lane == 0) ? ((wid > 0) ? lmf : -INFINITY) : lm;
    rm = __shfl_down(a00, 1);
    t  = __shfl(a10, 0);
    rm = (lane == 63) ? t : rm;
    proc4(a00, a01, a02, a03, lm, rm, base, v0, i0, v1);

    // group 1
    lm = __shfl_up(a13, 1);
    t  = __shfl(a03, 63);
    lm = (lane == 0) ? t : lm;
    rm = __shfl_down(a10, 1);
    t  = __shfl(a20, 0);
    rm = (lane == 63) ? t : rm;
    proc4(a10, a11, a12, a13, lm, rm, base + 256, v0, i0, v1);

    // group 2
    lm = __shfl_up(a23, 1);
    t  = __shfl(a13, 63);
    lm = (lane == 0) ? t : lm;
    rm = __shfl_down(a20, 1);
    t  = __shfl(a30, 0);
    rm = (lane == 63) ? t : rm;
    proc4(a20, a21, a22, a23, lm, rm, base + 512, v0, i0, v1);

    // group 3
    lm = __shfl_up(a33, 1);
    t  = __shfl(a23, 63);
    lm = (lane == 0) ? t : lm;
    rm = __shfl_down(a30, 1);
    rm = (lane == 63) ? ((wid < 3) ? rmf : -INFINITY) : rm;
    proc4(a30, a31, a32, a33, lm, rm, base + 768, v0, i0, v1);

    // wave butterfly top-2 merge (lexicographic on (value desc, index asc))
    #pragma unroll
    for (int off = 1; off < 64; off <<= 1) {
        const float ov0 = __shfl_xor(v0, off);
        const int   oi0 = __shfl_xor(i0, off);
        const float ov1 = __shfl_xor(v1, off);
        const bool big = (ov0 > v0) || (ov0 == v0 && oi0 < i0);
        const float loser = big ? v0 : ov0;
        v1 = fmaxf(fmaxf(v1, ov1), loser);
        v0 = big ? ov0 : v0;
        i0 = big ? oi0 : i0;
    }
}

// Merge the 4 per-wave results of one channel (LDS slots, uniform reads).
__device__ __forceinline__ void merge4(const float sv0c[4], const int si0c[4],
                                       const float sv1c[4],
                                       float& m0, int& mi, float& m1)
{
    m0 = sv0c[0]; mi = si0c[0]; m1 = sv1c[0];
    #pragma unroll
    for (int w = 1; w < 4; ++w) {
        const float b0 = sv0c[w]; const int bi = si0c[w]; const float b1 = sv1c[w];
        const bool big = (b0 > m0) || (b0 == m0 && bi < mi);
        const float loser = big ? m0 : b0;
        m1 = fmaxf(fmaxf(m1, b1), loser);
        m0 = big ? b0 : m0;
        mi = big ? bi : mi;
    }
}

__global__ __launch_bounds__(256) void detect_peaks_kernel(
    const float* __restrict__ xcorr,
    const int*   __restrict__ nlag_p,
    float* __restrict__ out)
{
    __shared__ float sv0[NC][4], sv1[NC][4];
    __shared__ int   si0[NC][4];

    const int bid  = blockIdx.x;           // (b, x)
    const int b    = bid >> 6;
    const int x    = bid & 63;
    const int tid  = threadIdx.x;
    const int lane = tid & 63;
    const int wid  = tid >> 6;

    const float* __restrict__ xr0 = xcorr + ((size_t)(b * NC) * NX + x) * NT;
    const float* __restrict__ xr1 = xr0 + CH_STRIDE;
    const float* __restrict__ xr2 = xr0 + 2 * CH_STRIDE;

    // ---- issue ALL loads up front: 12 dwordx4 + 6 uniform edge dwords ----
    Quad q0 = load_row(xr0, wid, lane);
    Quad q1 = load_row(xr1, wid, lane);
    Quad q2 = load_row(xr2, wid, lane);

    const int liE = (wid > 0) ? (wid << 10) - 1    : 0;
    const int riE = (wid < 3) ? (wid << 10) + 1024 : NT - 1;
    const float l0 = fabsf(xr0[liE]), r0 = fabsf(xr0[riE]);
    const float l1 = fabsf(xr1[liE]), r1 = fabsf(xr1[riE]);
    const float l2 = fabsf(xr2[liE]), r2 = fabsf(xr2[riE]);

    float v0, v1; int i0;

    scan_row(q0, l0, r0, wid, lane, v0, i0, v1);
    if (lane == 0) { sv0[0][wid] = v0; si0[0][wid] = i0; sv1[0][wid] = v1; }

    scan_row(q1, l1, r1, wid, lane, v0, i0, v1);
    if (lane == 0) { sv0[1][wid] = v0; si0[1][wid] = i0; sv1[1][wid] = v1; }

    scan_row(q2, l2, r2, wid, lane, v0, i0, v1);
    if (lane == 0) { sv0[2][wid] = v0; si0[2][wid] = i0; sv1[2][wid] = v1; }

    __syncthreads();   // the only barrier in the kernel

    // uniform epilogue (all threads redundantly; tid 0 writes)
    float m00, m01, m02, m10, m11, m12; int p0, p1, p2;
    merge4(sv0[0], si0[0], sv1[0], m00, p0, m10);
    merge4(sv0[1], si0[1], sv1[1], m01, p1, m11);
    merge4(sv0[2], si0[2], sv1[2], m02, p2, m12);

    const float w0 = (0.1f + 3.0f * (m00 - m10)) * (m00 * m00);
    const float w1 = (0.1f + 3.0f * (m01 - m11)) * (m01 * m01);
    const float w2 = (0.1f + 3.0f * (m02 - m12)) * (m02 * m02);

    // channel argmax, first occurrence (ascending c, strict >) — branch-free
    const bool t1 = w1 > w0;
    float bw = t1 ? w1 : w0;
    float bs = t1 ? m01 : m00;
    int   bp = t1 ? p1 : p0;
    const float* xrs = t1 ? xr1 : xr0;
    const bool t2 = w2 > bw;
    bw  = t2 ? w2 : bw;
    bs  = t2 ? m02 : bs;
    bp  = t2 ? p2 : bp;
    xrs = t2 ? xr2 : xrs;

    if (tid == 0) {
        // parabola through clipped neighbors of the selected peak
        const float ym1 = fabsf(xrs[bp > 0 ? bp - 1 : 0]);
        const float yp1 = fabsf(xrs[bp < NT - 1 ? bp + 1 : NT - 1]);
        const float A = 0.5f * (ym1 + yp1) - bs;   // <= 0 up to FP rounding
        const float B = 0.5f * (yp1 - ym1);
        const float C = bs;

        // closed-form grid argmax of yg=(A*xg+B)*xg+C over xg=linspace(-1,1,201):
        // evaluate the 4 grid points bracketing the vertex with the SAME FP
        // formula as the reference; first-max tie-break (ascending candidates).
        int gi; float bv;
        if (A == 0.0f) {
            gi = (B > 0.0f) ? 200 : 0;
            const float xg = 0.01f * (float)(gi - 100);
            bv = (A * xg + B) * xg + C;
        } else {
            float gv = (1.0f - 0.5f * B / A) * 100.0f;  // vertex in grid coords
            gv = fminf(fmaxf(gv, 0.0f), 200.0f);
            const int glo = (int)gv;
            bv = -INFINITY; gi = 0;
            #pragma unroll
            for (int d = -1; d <= 2; ++d) {
                int g = glo + d;
                g = g < 0 ? 0 : (g > 200 ? 200 : g);
                const float xg = 0.01f * (float)(g - 100);
                const float yg = (A * xg + B) * xg + C;
                if (yg > bv) { bv = yg; gi = g; }       // strict > = first occurrence
            }
        }

        const float fidx = (float)bp + 0.01f * (float)(gi - 100);
        const float nlagf = (float)(*nlag_p);
        const float shift_idx = fidx - nlagf;
        const int n = NB * NX;
        const int o = b * NX + x;
        out[0 * n + o] = bv;                  // max_cc (interpolated score)
        out[1 * n + o] = bw;                  // weight
        out[2 * n + o] = shift_idx / 100.0f;  // shift_t (SAMPLING_RATE = 100)
        out[3 * n + o] = shift_idx;           // shift_idx
    }
}

extern "C" void kernel_launch(void* const* d_in, const int* in_sizes, int n_in,
                              void* d_out, int out_size, void* d_ws, size_t ws_size,
                              hipStream_t stream) {
    const float* xcorr  = (const float*)d_in[0];
    const int*   nlag_p = (const int*)d_in[1];
    float* out = (float*)d_out;

    detect_peaks_kernel<<<NB * NX, 256, 0, stream>>>(xcorr, nlag_p, out);
}